// Round 1
// baseline (9756.859 us; speedup 1.0000x reference)
//
#include <hip/hip_runtime.h>

#define N_NODES 200000
#define IN_DIM 1433
#define HID 16
#define OUTD 7

// ---------------- K1: XW1 = X @ W1  (200000x1433 @ 1433x16) ----------------
// 64 rows per block, K chunked by 128, staged in LDS.
// thread t: row = t & 63, jg = t >> 6 (wave-uniform) -> 4 output cols each.
#define RPB 64
#define KC 128
#define NCHUNK 12          // 12*128 = 1536 >= 1433
#define XT_STRIDE 132      // 128 + 4 pad (16B-aligned, breaks bank aliasing)

__global__ __launch_bounds__(256) void gemm1_kernel(
    const float* __restrict__ X, const float* __restrict__ W1,
    float* __restrict__ XW1, int n)
{
    __shared__ float Xt[RPB][XT_STRIDE];   // 33.8 KB
    __shared__ float Wc[KC][HID];          // 8 KB

    const int tid = threadIdx.x;
    const int rloc = tid & 63;
    const int jg4 = (tid >> 6) << 2;       // wave-uniform: 0,4,8,12
    const long long rowbase = (long long)blockIdx.x * RPB;
    const long long row = rowbase + rloc;

    float acc0 = 0.f, acc1 = 0.f, acc2 = 0.f, acc3 = 0.f;

    for (int c = 0; c < NCHUNK; ++c) {
        const int k0 = c * KC;
        __syncthreads();
        // stage X tile: 64 rows x 128 cols, coalesced (128 consecutive per row)
        #pragma unroll
        for (int it = 0; it < (RPB * KC) / 256; ++it) {
            int idx = tid + it * 256;
            int r = idx >> 7, kk = idx & 127;
            long long gr = rowbase + r;
            int k = k0 + kk;
            float v = 0.f;
            if (gr < n && k < IN_DIM) v = X[gr * IN_DIM + k];
            Xt[r][kk] = v;
        }
        // stage W1 chunk: 128 x 16
        #pragma unroll
        for (int it = 0; it < (KC * HID) / 256; ++it) {
            int idx = tid + it * 256;
            int kk = idx >> 4, j = idx & 15;
            int k = k0 + kk;
            Wc[kk][j] = (k < IN_DIM) ? W1[k * HID + j] : 0.f;
        }
        __syncthreads();
        // compute: 32 iters of 4 k-steps
        #pragma unroll 4
        for (int i = 0; i < KC / 4; ++i) {
            const float4 xv = *(const float4*)&Xt[rloc][4 * i];
            const float4 w0 = *(const float4*)&Wc[4 * i + 0][jg4];
            const float4 w1 = *(const float4*)&Wc[4 * i + 1][jg4];
            const float4 w2 = *(const float4*)&Wc[4 * i + 2][jg4];
            const float4 w3 = *(const float4*)&Wc[4 * i + 3][jg4];
            acc0 = fmaf(xv.x, w0.x, acc0); acc1 = fmaf(xv.x, w0.y, acc1);
            acc2 = fmaf(xv.x, w0.z, acc2); acc3 = fmaf(xv.x, w0.w, acc3);
            acc0 = fmaf(xv.y, w1.x, acc0); acc1 = fmaf(xv.y, w1.y, acc1);
            acc2 = fmaf(xv.y, w1.z, acc2); acc3 = fmaf(xv.y, w1.w, acc3);
            acc0 = fmaf(xv.z, w2.x, acc0); acc1 = fmaf(xv.z, w2.y, acc1);
            acc2 = fmaf(xv.z, w2.z, acc2); acc3 = fmaf(xv.z, w2.w, acc3);
            acc0 = fmaf(xv.w, w3.x, acc0); acc1 = fmaf(xv.w, w3.y, acc1);
            acc2 = fmaf(xv.w, w3.z, acc2); acc3 = fmaf(xv.w, w3.w, acc3);
        }
    }
    if (row < n) {
        float4 r4 = make_float4(acc0, acc1, acc2, acc3);
        *(float4*)&XW1[row * HID + jg4] = r4;
    }
}

// ---------------- K2: h += scatter(vals[e] * XW1[cols[e],:]) ----------------
__global__ __launch_bounds__(256) void spmm1_kernel(
    const int* __restrict__ rows, const int* __restrict__ cols,
    const float* __restrict__ vals, const float* __restrict__ XW1,
    float* __restrict__ h, int nE)
{
    int e = blockIdx.x * 256 + threadIdx.x;
    if (e >= nE) return;
    int r = rows[e], c = cols[e];
    float v = vals[e];
    const float4* src = (const float4*)&XW1[(long long)c * HID];
    float* dst = &h[(long long)r * HID];
    #pragma unroll
    for (int q = 0; q < 4; ++q) {
        float4 x = src[q];
        atomicAdd(dst + 4 * q + 0, v * x.x);
        atomicAdd(dst + 4 * q + 1, v * x.y);
        atomicAdd(dst + 4 * q + 2, v * x.z);
        atomicAdd(dst + 4 * q + 3, v * x.w);
    }
}

// ------- K3: g = relu(h + b1) @ W2 ; out init = b2 (before spmm2 atomics) ----
__global__ __launch_bounds__(256) void layer2_kernel(
    const float* __restrict__ h, const float* __restrict__ b1,
    const float* __restrict__ W2, const float* __restrict__ b2,
    float* __restrict__ g, float* __restrict__ out, int n)
{
    int i = blockIdx.x * 256 + threadIdx.x;
    if (i >= n) return;
    float hv[HID];
    const float4* hp = (const float4*)&h[(long long)i * HID];
    #pragma unroll
    for (int q = 0; q < 4; ++q) {
        float4 x = hp[q];
        hv[4 * q + 0] = x.x; hv[4 * q + 1] = x.y;
        hv[4 * q + 2] = x.z; hv[4 * q + 3] = x.w;
    }
    #pragma unroll
    for (int j = 0; j < HID; ++j) {
        float t = hv[j] + b1[j];
        hv[j] = t > 0.f ? t : 0.f;
    }
    #pragma unroll
    for (int o = 0; o < OUTD; ++o) {
        float s = 0.f;
        #pragma unroll
        for (int j = 0; j < HID; ++j) s = fmaf(hv[j], W2[j * OUTD + o], s);
        g[(long long)i * OUTD + o] = s;
        out[(long long)i * OUTD + o] = b2[o];
    }
}

// ---------------- K4: out += scatter(vals[e] * g[cols[e],:]) ----------------
__global__ __launch_bounds__(256) void spmm2_kernel(
    const int* __restrict__ rows, const int* __restrict__ cols,
    const float* __restrict__ vals, const float* __restrict__ g,
    float* __restrict__ out, int nE)
{
    int e = blockIdx.x * 256 + threadIdx.x;
    if (e >= nE) return;
    int r = rows[e], c = cols[e];
    float v = vals[e];
    const float* src = &g[(long long)c * OUTD];
    float* dst = &out[(long long)r * OUTD];
    #pragma unroll
    for (int o = 0; o < OUTD; ++o) atomicAdd(dst + o, v * src[o]);
}

extern "C" void kernel_launch(void* const* d_in, const int* in_sizes, int n_in,
                              void* d_out, int out_size, void* d_ws, size_t ws_size,
                              hipStream_t stream)
{
    const int*   adj  = (const int*)d_in[0];    // [2, E] int32: rows then cols
    const float* vals = (const float*)d_in[1];  // [E]
    const float* X    = (const float*)d_in[2];  // [N, 1433]
    const float* W1   = (const float*)d_in[3];  // [1433, 16]
    const float* b1   = (const float*)d_in[4];  // [16]
    const float* W2   = (const float*)d_in[5];  // [16, 7]
    const float* b2   = (const float*)d_in[6];  // [7]
    float* out = (float*)d_out;

    const int E = in_sizes[1];           // 6,400,000
    const int N = in_sizes[2] / IN_DIM;  // 200,000
    const int* rows = adj;
    const int* cols = adj + E;

    float* XW1 = (float*)d_ws;                   // N*16 floats = 12.8 MB
    float* h   = XW1 + (size_t)N * HID;          // N*16 floats = 12.8 MB
    float* g   = h   + (size_t)N * HID;          // N*7  floats = 5.6 MB

    hipMemsetAsync(h, 0, (size_t)N * HID * sizeof(float), stream);

    gemm1_kernel<<<(N + RPB - 1) / RPB, 256, 0, stream>>>(X, W1, XW1, N);
    spmm1_kernel<<<(E + 255) / 256, 256, 0, stream>>>(rows, cols, vals, XW1, h, E);
    layer2_kernel<<<(N + 255) / 256, 256, 0, stream>>>(h, b1, W2, b2, g, out, N);
    spmm2_kernel<<<(E + 255) / 256, 256, 0, stream>>>(rows, cols, vals, g, out, E);
}